// Round 4
// baseline (965.691 us; speedup 1.0000x reference)
//
#include <hip/hip_runtime.h>
#include <cstddef>

// ---------------------------------------------------------------------------
// MultigridLayer: c/r bilinear downsample + steps pair-sum + AAt (bf16 MFMA,
// symmetric, Pinv folded as sqrt into columns) + D row-weighted-sumsq.
//
// Output layout (fp32, flat):
//   c   [2][1024][6]     @ 0         (12288)
//   r   [2][1024]        @ 12288     (2048)
//   sx  [2][31]          @ 14336     (62)
//   sy  [2][31]          @ 14398     (62)
//   AAt [1][4096][4096]  @ 14460     (16777216)
//   D   [2][4096]        @ 16791676  (8192)
//
// GEMM: triangular 128x128 tiles (528 pairs) x K-split 2 = 1056 blocks
// (~4.1 blocks/CU -> m97's latency-hiding regime), fp32 atomic accumulate
// into zero-initialized AAt. m97 2-barrier structure, T2 XOR swizzle.
// ---------------------------------------------------------------------------

#define NVAR 12288
#define NN   16384   // NUM_VAR + NUM_EPS (K dim of the GEMM)
#define MM   4096    // NUM_EPS (M=N of AAt)

typedef __bf16 bf8v __attribute__((ext_vector_type(8)));
typedef float  f4v  __attribute__((ext_vector_type(4)));
typedef unsigned short u16;

__device__ __forceinline__ void gld_lds16(const void* g, void* l) {
  __builtin_amdgcn_global_load_lds((const __attribute__((address_space(1))) void*)g,
                                   (__attribute__((address_space(3))) void*)l,
                                   16, 0, 0);
}

// round-to-nearest-even fp32 -> bf16 (finite values only)
__device__ __forceinline__ u16 f2bf(float x) {
  unsigned int u = __float_as_uint(x);
  u = (u + 0x7fffu + ((u >> 16) & 1u)) >> 16;
  return (u16)u;
}

// jax.image.resize linear+antialias, scale=1/2: taps at 2i-1..2i+2, raw
// weights {.25,.75,.75,.25}, out-of-range dropped, renormalized.
__device__ __forceinline__ void make_taps(int i, float w[4], int p[4]) {
  const float rw[4] = {0.25f, 0.75f, 0.75f, 0.25f};
  float s = 0.f;
#pragma unroll
  for (int t = 0; t < 4; ++t) {
    int pp = 2 * i - 1 + t;
    bool v = (pp >= 0) && (pp < 64);
    p[t] = v ? pp : 0;
    w[t] = v ? rw[t] : 0.f;
    s += w[t];
  }
  float inv = 1.f / s;
#pragma unroll
  for (int t = 0; t < 4; ++t) w[t] *= inv;
}

// --------------------------- zero AAt region -------------------------------
__global__ __launch_bounds__(256)
void zero_aat(float4* __restrict__ p) {
  const size_t i = (size_t)blockIdx.x * 256 + threadIdx.x;
#pragma unroll
  for (int k = 0; k < 8; ++k)
    p[i + (size_t)k * 524288] = float4{0.f, 0.f, 0.f, 0.f};
}

// --------------------------- small outputs --------------------------------
__global__ void small_ops(const float* __restrict__ coeffs,
                          const float* __restrict__ rhs,
                          const float* __restrict__ stx,
                          const float* __restrict__ sty,
                          float* __restrict__ out) {
  int idx = blockIdx.x * 256 + threadIdx.x;
  if (idx < 12288) {                       // c: [b][pix][o]
    int b = idx / 6144, rem = idx % 6144;
    int pix = rem / 6, o = rem % 6;
    int yi = pix >> 5, xi = pix & 31;
    float wy[4], wx[4]; int py[4], px[4];
    make_taps(yi, wy, py);
    make_taps(xi, wx, px);
    float acc = 0.f;
#pragma unroll
    for (int dy = 0; dy < 4; ++dy) {
      float sx = 0.f;
#pragma unroll
      for (int dx = 0; dx < 4; ++dx)
        sx += wx[dx] * coeffs[((size_t)b * 4096 + py[dy] * 64 + px[dx]) * 6 + o];
      acc += wy[dy] * sx;
    }
    out[idx] = acc;
  } else if (idx < 14336) {                // r: [b][pix]
    int j = idx - 12288;
    int b = j >> 10, pix = j & 1023;
    int yi = pix >> 5, xi = pix & 31;
    float wy[4], wx[4]; int py[4], px[4];
    make_taps(yi, wy, py);
    make_taps(xi, wx, px);
    float acc = 0.f;
#pragma unroll
    for (int dy = 0; dy < 4; ++dy) {
      float sx = 0.f;
#pragma unroll
      for (int dx = 0; dx < 4; ++dx)
        sx += wx[dx] * rhs[(size_t)b * 4096 + py[dy] * 64 + px[dx]];
      acc += wy[dy] * sx;
    }
    out[idx] = acc;
  } else if (idx < 14460) {                // sx then sy: pair sums
    int j = idx - 14336;
    if (j < 62) {
      int b = j / 31, i = j % 31;
      out[idx] = stx[b * 63 + 2 * i] + stx[b * 63 + 2 * i + 1];
    } else {
      j -= 62;
      int b = j / 31, i = j % 31;
      out[idx] = sty[b * 63 + 2 * i] + sty[b * 63 + 2 * i + 1];
    }
  }
}

// ------------------- D + fused bf16*sqrt(Pinv) convert ---------------------
// one block per (row m, batch b); 256 threads read the 16384-float row.
__global__ __launch_bounds__(256)
void d_and_convert(const float* __restrict__ A, float* __restrict__ Dout,
                   u16* __restrict__ Abf, const int useWs) {
  const int m = blockIdx.x, b = blockIdx.y;
  const int t = threadIdx.x;
  const float PV = 1.0f / 1e-5f, PE = 1.0f / 1e5f;
  const float SV = sqrtf(PV), SE = sqrtf(PE);
  const float* __restrict__ row = A + ((size_t)b * MM + m) * NN;
  const bool wr = (b == 0) && useWs;
  float acc = 0.f;
#pragma unroll
  for (int i = 0; i < 16; ++i) {
    const int n = i * 1024 + t * 4;        // boundary 12288 = iter 12 exactly
    const float4 v = *(const float4*)(row + n);
    const bool isv = n < NVAR;
    const float pv = isv ? PV : PE;
    acc += pv * (v.x * v.x + v.y * v.y + v.z * v.z + v.w * v.w);
    if (wr) {
      const float s = isv ? SV : SE;
      ushort4 o;
      o.x = f2bf(v.x * s); o.y = f2bf(v.y * s);
      o.z = f2bf(v.z * s); o.w = f2bf(v.w * s);
      *(ushort4*)(Abf + (size_t)m * NN + n) = o;
    }
  }
#pragma unroll
  for (int off = 32; off > 0; off >>= 1) acc += __shfl_down(acc, off);
  __shared__ float red[4];
  if ((t & 63) == 0) red[t >> 6] = acc;
  __syncthreads();
  if (t == 0) Dout[(size_t)b * MM + m] = red[0] + red[1] + red[2] + red[3];
}

// ------------------------------- AAt GEMM ---------------------------------
// C += X Xt (K-half) with X = bf16(A[0] * sqrt(Pinv)) [4096 x 16384].
// 128x128 tile, BK=64, 4 waves each computing a 64x64 sub-tile via
// 4x4 fragments of mfma_f32_16x16x32_bf16. Grid = 528 triangular pairs x
// 2 K-halves, XCD-swizzled; epilogue = fp32 HW atomics (tile + mirror).
// T2 bank-conflict fix: 16B-chunk XOR swizzle applied on the GLOBAL source
// address (global_load_lds writes linearly) and on the ds_read address.
template <int USE_WS>
__global__ __launch_bounds__(256)
void gemm_aat(const u16* __restrict__ Abf, const float* __restrict__ A0,
              float* __restrict__ C) {
  // ---- XCD swizzle (1056 % 8 == 0 -> simple remap is bijective) ----
  const int k0 = blockIdx.x;
  const int kid = (k0 & 7) * 132 + (k0 >> 3);
  const int half = kid & 1;          // K-half: 0 -> [0,8192), 1 -> [8192,16384)
  const int pair = kid >> 1;         // 0..527 triangular pair
  // ---- triangular decode over 32 tiles: S(i) = (65*i - i*i)/2 ----
  int bi = (int)((65.0f - sqrtf(65.0f * 65.0f - 8.0f * (float)pair)) * 0.5f);
  while (((65 * (bi + 1) - (bi + 1) * (bi + 1)) >> 1) <= pair) ++bi;
  while (((65 * bi - bi * bi) >> 1) > pair) --bi;
  const int bj = bi + (pair - ((65 * bi - bi * bi) >> 1));

  __shared__ u16 ldsA[128 * 64];
  __shared__ u16 ldsB[128 * 64];
  const int t = threadIdx.x;
  const int lane = t & 63;
  const int wave = t >> 6;
  const int wr = (wave >> 1) * 64;   // wave's row offset in tile
  const int wc = (wave & 1) * 64;    // wave's col offset in tile

  f4v acc[4][4];
#pragma unroll
  for (int i = 0; i < 4; ++i)
#pragma unroll
    for (int j = 0; j < 4; ++j)
      acc[i][j] = f4v{0.f, 0.f, 0.f, 0.f};

  // staging: thread t fills LDS row (t>>3), 16B chunk (t&7) of each 32-row
  // block; source column chunk is XOR-swizzled so that
  // LDS[row][c] = global[row][c ^ (row&7)]  (chunks of 8 elems / 16B)
  const int srow = t >> 3;
  const int scol = (((t & 7) ^ (srow & 7)) * 8);   // swizzled source chunk
  const size_t rA = (size_t)bi * 128 + srow;
  const size_t rB = (size_t)bj * 128 + srow;
  const int ldse = t * 8;            // linear per-thread LDS elem offset

  const float SV = sqrtf(1.0f / 1e-5f);
  const float SE = sqrtf(1.0f / 1e5f);

  // ds_read swizzle: row r, chunk (kk*4+q) -> chunk ^ (r&7); r&7 == p&7
  const int q = lane >> 4;
  const int p = lane & 15;
  const int csw0 = ((0 * 4 + q) ^ (p & 7)) * 8;    // kk=0 chunk offset (elems)
  const int csw1 = ((1 * 4 + q) ^ (p & 7)) * 8;    // kk=1

  const int kb0 = half * 8192;       // this block's K-range base

  for (int kt = 0; kt < 128; ++kt) {
    const int kb = kb0 + kt * 64;
    if (USE_WS) {
#pragma unroll
      for (int i = 0; i < 4; ++i) {
        gld_lds16(Abf + (rA + i * 32) * NN + kb + scol, &ldsA[i * 2048 + ldse]);
        gld_lds16(Abf + (rB + i * 32) * NN + kb + scol, &ldsB[i * 2048 + ldse]);
      }
    } else {
      // fallback: reg-stage fp32 -> scaled bf16 -> LDS (same swizzle)
      const int n = kb + scol;                    // 8-chunk never crosses 12288
      const float s = (n < NVAR) ? SV : SE;
#pragma unroll
      for (int i = 0; i < 4; ++i) {
        const float* ga = A0 + (rA + i * 32) * NN + n;
        const float* gb = A0 + (rB + i * 32) * NN + n;
        const float4 a0 = ((const float4*)ga)[0], a1 = ((const float4*)ga)[1];
        const float4 b0 = ((const float4*)gb)[0], b1 = ((const float4*)gb)[1];
        u16* dA = &ldsA[i * 2048 + ldse];
        u16* dB = &ldsB[i * 2048 + ldse];
        dA[0] = f2bf(a0.x * s); dA[1] = f2bf(a0.y * s);
        dA[2] = f2bf(a0.z * s); dA[3] = f2bf(a0.w * s);
        dA[4] = f2bf(a1.x * s); dA[5] = f2bf(a1.y * s);
        dA[6] = f2bf(a1.z * s); dA[7] = f2bf(a1.w * s);
        dB[0] = f2bf(b0.x * s); dB[1] = f2bf(b0.y * s);
        dB[2] = f2bf(b0.z * s); dB[3] = f2bf(b0.w * s);
        dB[4] = f2bf(b1.x * s); dB[5] = f2bf(b1.y * s);
        dB[6] = f2bf(b1.z * s); dB[7] = f2bf(b1.w * s);
      }
    }
    __syncthreads();
#pragma unroll
    for (int kk = 0; kk < 2; ++kk) {
      const int co = kk ? csw1 : csw0;
      bf8v af[4], bfr[4];
#pragma unroll
      for (int i = 0; i < 4; ++i)
        af[i] = *(const bf8v*)&ldsA[(wr + i * 16 + p) * 64 + co];
#pragma unroll
      for (int j = 0; j < 4; ++j)
        bfr[j] = *(const bf8v*)&ldsB[(wc + j * 16 + p) * 64 + co];
#pragma unroll
      for (int i = 0; i < 4; ++i)
#pragma unroll
        for (int j = 0; j < 4; ++j)
          acc[i][j] = __builtin_amdgcn_mfma_f32_16x16x32_bf16(
              af[i], bfr[j], acc[i][j], 0, 0, 0);
    }
    __syncthreads();
  }

  // epilogue: C/D layout col=lane&15 (=p), row=(lane>>4)*4+reg (=q*4+r)
  // fp32 HW atomic accumulate (two K-halves add into the same tile).
  const int cc = p;
  const int cr = q * 4;
#pragma unroll
  for (int i = 0; i < 4; ++i)
#pragma unroll
    for (int j = 0; j < 4; ++j)
#pragma unroll
      for (int r = 0; r < 4; ++r) {
        const int gr = bi * 128 + wr + i * 16 + cr + r;
        const int gc = bj * 128 + wc + j * 16 + cc;
        unsafeAtomicAdd(&C[(size_t)gr * MM + gc], acc[i][j][r]);
      }
  if (bi != bj) {
#pragma unroll
    for (int i = 0; i < 4; ++i)
#pragma unroll
      for (int j = 0; j < 4; ++j)
#pragma unroll
        for (int r = 0; r < 4; ++r) {
          const int gr = bi * 128 + wr + i * 16 + cr + r;
          const int gc = bj * 128 + wc + j * 16 + cc;
          unsafeAtomicAdd(&C[(size_t)gc * MM + gr], acc[i][j][r]);
        }
  }
}

// ------------------------------- launch ------------------------------------
extern "C" void kernel_launch(void* const* d_in, const int* in_sizes, int n_in,
                              void* d_out, int out_size, void* d_ws,
                              size_t ws_size, hipStream_t stream) {
  const float* coeffs = (const float*)d_in[0];
  const float* rhs    = (const float*)d_in[1];
  const float* stx    = (const float*)d_in[2];
  const float* sty    = (const float*)d_in[3];
  const float* A      = (const float*)d_in[4];

  float* out    = (float*)d_out;
  float* outAAt = out + 14460;
  float* outD   = out + 16791676;

  const size_t need = (size_t)MM * NN * sizeof(u16);  // 128 MiB
  const int useWs = (ws_size >= need) ? 1 : 0;
  u16* Abf = (u16*)d_ws;

  zero_aat<<<dim3(2048), dim3(256), 0, stream>>>((float4*)outAAt);
  small_ops<<<dim3(57), dim3(256), 0, stream>>>(coeffs, rhs, stx, sty, out);
  d_and_convert<<<dim3(MM, 2), dim3(256), 0, stream>>>(A, outD, Abf, useWs);
  if (useWs)
    gemm_aat<1><<<dim3(1056), dim3(256), 0, stream>>>(Abf, A, outAAt);
  else
    gemm_aat<0><<<dim3(1056), dim3(256), 0, stream>>>(Abf, A, outAAt);
}

// Round 5
// 671.969 us; speedup vs baseline: 1.4371x; 1.4371x over previous
//
#include <hip/hip_runtime.h>
#include <cstddef>

// ---------------------------------------------------------------------------
// MultigridLayer: c/r bilinear downsample + steps pair-sum + AAt (bf16 MFMA,
// symmetric, Pinv folded as sqrt into columns) + D row-weighted-sumsq.
//
// Output layout (fp32, flat):
//   c   [2][1024][6]     @ 0         (12288)
//   r   [2][1024]        @ 12288     (2048)
//   sx  [2][31]          @ 14336     (62)
//   sy  [2][31]          @ 14398     (62)
//   AAt [1][4096][4096]  @ 14460     (16777216)
//   D   [2][4096]        @ 16791676  (8192)
//
// GEMM: triangular 128x128 tiles (528 blocks), m97 fragment structure +
// T2 XOR swizzle (conflicts = 0 measured) + T4 counted-vmcnt double buffer:
// raw s_barrier, s_waitcnt vmcnt(8) -- never vmcnt(0) in the main loop, so
// next-tile global_load_lds stay in flight across barriers (the documented
// fix for the m97 barrier-drain stall).
// ---------------------------------------------------------------------------

#define NVAR 12288
#define NN   16384   // NUM_VAR + NUM_EPS (K dim of the GEMM)
#define MM   4096    // NUM_EPS (M=N of AAt)

typedef __bf16 bf8v __attribute__((ext_vector_type(8)));
typedef float  f4v  __attribute__((ext_vector_type(4)));
typedef unsigned short u16;

__device__ __forceinline__ void gld_lds16(const void* g, void* l) {
  __builtin_amdgcn_global_load_lds((const __attribute__((address_space(1))) void*)g,
                                   (__attribute__((address_space(3))) void*)l,
                                   16, 0, 0);
}

// round-to-nearest-even fp32 -> bf16 (finite values only)
__device__ __forceinline__ u16 f2bf(float x) {
  unsigned int u = __float_as_uint(x);
  u = (u + 0x7fffu + ((u >> 16) & 1u)) >> 16;
  return (u16)u;
}

// jax.image.resize linear+antialias, scale=1/2: taps at 2i-1..2i+2, raw
// weights {.25,.75,.75,.25}, out-of-range dropped, renormalized.
__device__ __forceinline__ void make_taps(int i, float w[4], int p[4]) {
  const float rw[4] = {0.25f, 0.75f, 0.75f, 0.25f};
  float s = 0.f;
#pragma unroll
  for (int t = 0; t < 4; ++t) {
    int pp = 2 * i - 1 + t;
    bool v = (pp >= 0) && (pp < 64);
    p[t] = v ? pp : 0;
    w[t] = v ? rw[t] : 0.f;
    s += w[t];
  }
  float inv = 1.f / s;
#pragma unroll
  for (int t = 0; t < 4; ++t) w[t] *= inv;
}

// --------------------------- small outputs --------------------------------
__global__ void small_ops(const float* __restrict__ coeffs,
                          const float* __restrict__ rhs,
                          const float* __restrict__ stx,
                          const float* __restrict__ sty,
                          float* __restrict__ out) {
  int idx = blockIdx.x * 256 + threadIdx.x;
  if (idx < 12288) {                       // c: [b][pix][o]
    int b = idx / 6144, rem = idx % 6144;
    int pix = rem / 6, o = rem % 6;
    int yi = pix >> 5, xi = pix & 31;
    float wy[4], wx[4]; int py[4], px[4];
    make_taps(yi, wy, py);
    make_taps(xi, wx, px);
    float acc = 0.f;
#pragma unroll
    for (int dy = 0; dy < 4; ++dy) {
      float sx = 0.f;
#pragma unroll
      for (int dx = 0; dx < 4; ++dx)
        sx += wx[dx] * coeffs[((size_t)b * 4096 + py[dy] * 64 + px[dx]) * 6 + o];
      acc += wy[dy] * sx;
    }
    out[idx] = acc;
  } else if (idx < 14336) {                // r: [b][pix]
    int j = idx - 12288;
    int b = j >> 10, pix = j & 1023;
    int yi = pix >> 5, xi = pix & 31;
    float wy[4], wx[4]; int py[4], px[4];
    make_taps(yi, wy, py);
    make_taps(xi, wx, px);
    float acc = 0.f;
#pragma unroll
    for (int dy = 0; dy < 4; ++dy) {
      float sx = 0.f;
#pragma unroll
      for (int dx = 0; dx < 4; ++dx)
        sx += wx[dx] * rhs[(size_t)b * 4096 + py[dy] * 64 + px[dx]];
      acc += wy[dy] * sx;
    }
    out[idx] = acc;
  } else if (idx < 14460) {                // sx then sy: pair sums
    int j = idx - 14336;
    if (j < 62) {
      int b = j / 31, i = j % 31;
      out[idx] = stx[b * 63 + 2 * i] + stx[b * 63 + 2 * i + 1];
    } else {
      j -= 62;
      int b = j / 31, i = j % 31;
      out[idx] = sty[b * 63 + 2 * i] + sty[b * 63 + 2 * i + 1];
    }
  }
}

// ------------------- D + fused bf16*sqrt(Pinv) convert ---------------------
// one block per (row m, batch b); 256 threads read the 16384-float row.
__global__ __launch_bounds__(256)
void d_and_convert(const float* __restrict__ A, float* __restrict__ Dout,
                   u16* __restrict__ Abf, const int useWs) {
  const int m = blockIdx.x, b = blockIdx.y;
  const int t = threadIdx.x;
  const float PV = 1.0f / 1e-5f, PE = 1.0f / 1e5f;
  const float SV = sqrtf(PV), SE = sqrtf(PE);
  const float* __restrict__ row = A + ((size_t)b * MM + m) * NN;
  const bool wr = (b == 0) && useWs;
  float acc = 0.f;
#pragma unroll
  for (int i = 0; i < 16; ++i) {
    const int n = i * 1024 + t * 4;        // boundary 12288 = iter 12 exactly
    const float4 v = *(const float4*)(row + n);
    const bool isv = n < NVAR;
    const float pv = isv ? PV : PE;
    acc += pv * (v.x * v.x + v.y * v.y + v.z * v.z + v.w * v.w);
    if (wr) {
      const float s = isv ? SV : SE;
      ushort4 o;
      o.x = f2bf(v.x * s); o.y = f2bf(v.y * s);
      o.z = f2bf(v.z * s); o.w = f2bf(v.w * s);
      *(ushort4*)(Abf + (size_t)m * NN + n) = o;
    }
  }
#pragma unroll
  for (int off = 32; off > 0; off >>= 1) acc += __shfl_down(acc, off);
  __shared__ float red[4];
  if ((t & 63) == 0) red[t >> 6] = acc;
  __syncthreads();
  if (t == 0) Dout[(size_t)b * MM + m] = red[0] + red[1] + red[2] + red[3];
}

// ------------------------------- AAt GEMM ---------------------------------
// C = X Xt with X = bf16(A[0] * sqrt(Pinv)) [4096 x 16384].
// 128x128 tile, BK=64, 4 waves each computing a 64x64 sub-tile via
// 4x4 fragments of mfma_f32_16x16x32_bf16. Triangular grid (528 blocks,
// XCD-swizzled), mirror-write both triangles, plain stores.
// Double-buffered LDS + counted vmcnt(8) + raw s_barrier (T4).
template <int USE_WS>
__global__ __launch_bounds__(256)
void gemm_aat(const u16* __restrict__ Abf, const float* __restrict__ A0,
              float* __restrict__ C) {
  // ---- XCD swizzle (528 % 8 == 0 -> simple remap is bijective) ----
  const int k0 = blockIdx.x;
  const int kid = (k0 & 7) * 66 + (k0 >> 3);
  // ---- triangular decode: S(i) = (65*i - i*i)/2, bi s.t. S(bi)<=kid ----
  int bi = (int)((65.0f - sqrtf(65.0f * 65.0f - 8.0f * (float)kid)) * 0.5f);
  while (((65 * (bi + 1) - (bi + 1) * (bi + 1)) >> 1) <= kid) ++bi;
  while (((65 * bi - bi * bi) >> 1) > kid) --bi;
  const int bj = bi + (kid - ((65 * bi - bi * bi) >> 1));

  __shared__ u16 ldsA[2][128 * 64];
  __shared__ u16 ldsB[2][128 * 64];
  const int t = threadIdx.x;
  const int lane = t & 63;
  const int wave = t >> 6;
  const int wr = (wave >> 1) * 64;   // wave's row offset in tile
  const int wc = (wave & 1) * 64;    // wave's col offset in tile

  f4v acc[4][4];
#pragma unroll
  for (int i = 0; i < 4; ++i)
#pragma unroll
    for (int j = 0; j < 4; ++j)
      acc[i][j] = f4v{0.f, 0.f, 0.f, 0.f};

  // staging: thread t fills LDS row (t>>3), 16B chunk (t&7) of each 32-row
  // block; source column chunk is XOR-swizzled so that
  // LDS[row][c] = global[row][c ^ (row&7)]  (chunks of 8 elems / 16B)
  const int srow = t >> 3;
  const int scol = (((t & 7) ^ (srow & 7)) * 8);   // swizzled source chunk
  const size_t rA = (size_t)bi * 128 + srow;
  const size_t rB = (size_t)bj * 128 + srow;
  const int ldse = t * 8;            // linear per-thread LDS elem offset

  const float SV = sqrtf(1.0f / 1e-5f);
  const float SE = sqrtf(1.0f / 1e5f);

  // ds_read swizzle: row r, chunk (kk*4+q) -> chunk ^ (r&7); r&7 == p&7
  const int q = lane >> 4;
  const int p = lane & 15;
  const int csw0 = ((0 * 4 + q) ^ (p & 7)) * 8;    // kk=0 chunk offset (elems)
  const int csw1 = ((1 * 4 + q) ^ (p & 7)) * 8;    // kk=1

  // per-wave loads per STAGE: 8 global_load_lds (USE_WS path)
  auto STAGE = [&](int d, int kt) {
    const int kb = kt * 64;
    if (USE_WS) {
#pragma unroll
      for (int i = 0; i < 4; ++i) {
        gld_lds16(Abf + (rA + i * 32) * NN + kb + scol,
                  &ldsA[d][i * 2048 + ldse]);
        gld_lds16(Abf + (rB + i * 32) * NN + kb + scol,
                  &ldsB[d][i * 2048 + ldse]);
      }
    } else {
      const int n = kb + scol;                    // 8-chunk never crosses 12288
      const float s = (n < NVAR) ? SV : SE;
#pragma unroll
      for (int i = 0; i < 4; ++i) {
        const float* ga = A0 + (rA + i * 32) * NN + n;
        const float* gb = A0 + (rB + i * 32) * NN + n;
        const float4 a0 = ((const float4*)ga)[0], a1 = ((const float4*)ga)[1];
        const float4 b0 = ((const float4*)gb)[0], b1 = ((const float4*)gb)[1];
        u16* dA = &ldsA[d][i * 2048 + ldse];
        u16* dB = &ldsB[d][i * 2048 + ldse];
        dA[0] = f2bf(a0.x * s); dA[1] = f2bf(a0.y * s);
        dA[2] = f2bf(a0.z * s); dA[3] = f2bf(a0.w * s);
        dA[4] = f2bf(a1.x * s); dA[5] = f2bf(a1.y * s);
        dA[6] = f2bf(a1.z * s); dA[7] = f2bf(a1.w * s);
        dB[0] = f2bf(b0.x * s); dB[1] = f2bf(b0.y * s);
        dB[2] = f2bf(b0.z * s); dB[3] = f2bf(b0.w * s);
        dB[4] = f2bf(b1.x * s); dB[5] = f2bf(b1.y * s);
        dB[6] = f2bf(b1.z * s); dB[7] = f2bf(b1.w * s);
      }
    }
  };

  auto COMPUTE = [&](int d) {
#pragma unroll
    for (int kk = 0; kk < 2; ++kk) {
      const int co = kk ? csw1 : csw0;
      bf8v af[4], bfr[4];
#pragma unroll
      for (int i = 0; i < 4; ++i)
        af[i] = *(const bf8v*)&ldsA[d][(wr + i * 16 + p) * 64 + co];
#pragma unroll
      for (int j = 0; j < 4; ++j)
        bfr[j] = *(const bf8v*)&ldsB[d][(wc + j * 16 + p) * 64 + co];
#pragma unroll
      for (int i = 0; i < 4; ++i)
#pragma unroll
        for (int j = 0; j < 4; ++j)
          acc[i][j] = __builtin_amdgcn_mfma_f32_16x16x32_bf16(
              af[i], bfr[j], acc[i][j], 0, 0, 0);
    }
  };

  // prologue: fill both buffers (16 in-flight loads per wave on WS path)
  STAGE(0, 0);
  STAGE(1, 1);

  // main loop: counted vmcnt keeps next-tile loads in flight across barriers
  for (int kt = 0; kt < 255; ++kt) {
    const int d = kt & 1;
    if (USE_WS)
      asm volatile("s_waitcnt vmcnt(8)" ::: "memory");  // cur buffer retired
    else
      asm volatile("s_waitcnt vmcnt(0) lgkmcnt(0)" ::: "memory");
    __builtin_amdgcn_s_barrier();
    asm volatile("" ::: "memory");
    COMPUTE(d);
    asm volatile("" ::: "memory");
    __builtin_amdgcn_s_barrier();       // all waves done reading buf d
    asm volatile("" ::: "memory");
    if (kt + 2 < 256) STAGE(d, kt + 2); // overwrite buf d for step kt+2
  }
  // final step (kt = 255, buffer 1): drain everything
  asm volatile("s_waitcnt vmcnt(0) lgkmcnt(0)" ::: "memory");
  __builtin_amdgcn_s_barrier();
  asm volatile("" ::: "memory");
  COMPUTE(1);

  // epilogue: C/D layout col=lane&15 (=p), row=(lane>>4)*4+reg (=q*4+r)
  const int cc = p;
  const int cr = q * 4;
#pragma unroll
  for (int i = 0; i < 4; ++i)
#pragma unroll
    for (int j = 0; j < 4; ++j)
#pragma unroll
      for (int r = 0; r < 4; ++r) {
        const int gr = bi * 128 + wr + i * 16 + cr + r;
        const int gc = bj * 128 + wc + j * 16 + cc;
        C[(size_t)gr * MM + gc] = acc[i][j][r];
      }
  if (bi != bj) {
#pragma unroll
    for (int i = 0; i < 4; ++i)
#pragma unroll
      for (int j = 0; j < 4; ++j)
#pragma unroll
        for (int r = 0; r < 4; ++r) {
          const int gr = bi * 128 + wr + i * 16 + cr + r;
          const int gc = bj * 128 + wc + j * 16 + cc;
          C[(size_t)gc * MM + gr] = acc[i][j][r];
        }
  }
}

// ------------------------------- launch ------------------------------------
extern "C" void kernel_launch(void* const* d_in, const int* in_sizes, int n_in,
                              void* d_out, int out_size, void* d_ws,
                              size_t ws_size, hipStream_t stream) {
  const float* coeffs = (const float*)d_in[0];
  const float* rhs    = (const float*)d_in[1];
  const float* stx    = (const float*)d_in[2];
  const float* sty    = (const float*)d_in[3];
  const float* A      = (const float*)d_in[4];

  float* out    = (float*)d_out;
  float* outAAt = out + 14460;
  float* outD   = out + 16791676;

  const size_t need = (size_t)MM * NN * sizeof(u16);  // 128 MiB
  const int useWs = (ws_size >= need) ? 1 : 0;
  u16* Abf = (u16*)d_ws;

  small_ops<<<dim3(57), dim3(256), 0, stream>>>(coeffs, rhs, stx, sty, out);
  d_and_convert<<<dim3(MM, 2), dim3(256), 0, stream>>>(A, outD, Abf, useWs);
  if (useWs)
    gemm_aat<1><<<dim3(528), dim3(256), 0, stream>>>(Abf, A, outAAt);
  else
    gemm_aat<0><<<dim3(528), dim3(256), 0, stream>>>(Abf, A, outAAt);
}

// Round 6
// 555.783 us; speedup vs baseline: 1.7375x; 1.2090x over previous
//
#include <hip/hip_runtime.h>
#include <cstddef>

// ---------------------------------------------------------------------------
// MultigridLayer: c/r bilinear downsample + steps pair-sum + AAt (bf16 MFMA,
// symmetric, Pinv folded as sqrt into columns) + D row-weighted-sumsq.
//
// Output layout (fp32, flat):
//   c   [2][1024][6]     @ 0         (12288)
//   r   [2][1024]        @ 12288     (2048)
//   sx  [2][31]          @ 14336     (62)
//   sy  [2][31]          @ 14398     (62)
//   AAt [1][4096][4096]  @ 14460     (16777216)
//   D   [2][4096]        @ 16791676  (8192)
//
// GEMM work decomposition (no atomics, 4 blocks/CU):
//   1024 blocks = 32 diagonal tiles (full K) + 496 strict-upper pairs x 2
//   K-halves. half1 -> partial to true upper tile; half0 -> partial
//   (un-transposed) to the mirror (lower) slot. reduceA: upper += lowerSlot.
//   reduceB: lowerSlot = upper^T (LDS-staged transpose). m97 2-barrier body,
//   T2 XOR swizzle (bank conflicts = 0 measured).
// ---------------------------------------------------------------------------

#define NVAR 12288
#define NN   16384   // NUM_VAR + NUM_EPS (K dim of the GEMM)
#define MM   4096    // NUM_EPS (M=N of AAt)

typedef __bf16 bf8v __attribute__((ext_vector_type(8)));
typedef float  f4v  __attribute__((ext_vector_type(4)));
typedef unsigned short u16;

__device__ __forceinline__ void gld_lds16(const void* g, void* l) {
  __builtin_amdgcn_global_load_lds((const __attribute__((address_space(1))) void*)g,
                                   (__attribute__((address_space(3))) void*)l,
                                   16, 0, 0);
}

// round-to-nearest-even fp32 -> bf16 (finite values only)
__device__ __forceinline__ u16 f2bf(float x) {
  unsigned int u = __float_as_uint(x);
  u = (u + 0x7fffu + ((u >> 16) & 1u)) >> 16;
  return (u16)u;
}

// jax.image.resize linear+antialias, scale=1/2: taps at 2i-1..2i+2, raw
// weights {.25,.75,.75,.25}, out-of-range dropped, renormalized.
__device__ __forceinline__ void make_taps(int i, float w[4], int p[4]) {
  const float rw[4] = {0.25f, 0.75f, 0.75f, 0.25f};
  float s = 0.f;
#pragma unroll
  for (int t = 0; t < 4; ++t) {
    int pp = 2 * i - 1 + t;
    bool v = (pp >= 0) && (pp < 64);
    p[t] = v ? pp : 0;
    w[t] = v ? rw[t] : 0.f;
    s += w[t];
  }
  float inv = 1.f / s;
#pragma unroll
  for (int t = 0; t < 4; ++t) w[t] *= inv;
}

// strict-upper pair decode over a 32x32 tile grid: pair p -> (bi, bj), bi<bj
// C(i) = i*(63-i)/2 pairs before row i.
__device__ __forceinline__ void pair_decode(int pair, int& bi, int& bj) {
  int i = 0;
  while (((i + 1) * (63 - (i + 1))) / 2 <= pair) ++i;
  bi = i;
  bj = i + 1 + (pair - (i * (63 - i)) / 2);
}

// --------------------------- small outputs --------------------------------
__global__ void small_ops(const float* __restrict__ coeffs,
                          const float* __restrict__ rhs,
                          const float* __restrict__ stx,
                          const float* __restrict__ sty,
                          float* __restrict__ out) {
  int idx = blockIdx.x * 256 + threadIdx.x;
  if (idx < 12288) {                       // c: [b][pix][o]
    int b = idx / 6144, rem = idx % 6144;
    int pix = rem / 6, o = rem % 6;
    int yi = pix >> 5, xi = pix & 31;
    float wy[4], wx[4]; int py[4], px[4];
    make_taps(yi, wy, py);
    make_taps(xi, wx, px);
    float acc = 0.f;
#pragma unroll
    for (int dy = 0; dy < 4; ++dy) {
      float sx = 0.f;
#pragma unroll
      for (int dx = 0; dx < 4; ++dx)
        sx += wx[dx] * coeffs[((size_t)b * 4096 + py[dy] * 64 + px[dx]) * 6 + o];
      acc += wy[dy] * sx;
    }
    out[idx] = acc;
  } else if (idx < 14336) {                // r: [b][pix]
    int j = idx - 12288;
    int b = j >> 10, pix = j & 1023;
    int yi = pix >> 5, xi = pix & 31;
    float wy[4], wx[4]; int py[4], px[4];
    make_taps(yi, wy, py);
    make_taps(xi, wx, px);
    float acc = 0.f;
#pragma unroll
    for (int dy = 0; dy < 4; ++dy) {
      float sx = 0.f;
#pragma unroll
      for (int dx = 0; dx < 4; ++dx)
        sx += wx[dx] * rhs[(size_t)b * 4096 + py[dy] * 64 + px[dx]];
      acc += wy[dy] * sx;
    }
    out[idx] = acc;
  } else if (idx < 14460) {                // sx then sy: pair sums
    int j = idx - 14336;
    if (j < 62) {
      int b = j / 31, i = j % 31;
      out[idx] = stx[b * 63 + 2 * i] + stx[b * 63 + 2 * i + 1];
    } else {
      j -= 62;
      int b = j / 31, i = j % 31;
      out[idx] = sty[b * 63 + 2 * i] + sty[b * 63 + 2 * i + 1];
    }
  }
}

// ------------------- D + fused bf16*sqrt(Pinv) convert ---------------------
// one block per (row m, batch b); 256 threads read the 16384-float row.
__global__ __launch_bounds__(256)
void d_and_convert(const float* __restrict__ A, float* __restrict__ Dout,
                   u16* __restrict__ Abf, const int useWs) {
  const int m = blockIdx.x, b = blockIdx.y;
  const int t = threadIdx.x;
  const float PV = 1.0f / 1e-5f, PE = 1.0f / 1e5f;
  const float SV = sqrtf(PV), SE = sqrtf(PE);
  const float* __restrict__ row = A + ((size_t)b * MM + m) * NN;
  const bool wr = (b == 0) && useWs;
  float acc = 0.f;
#pragma unroll
  for (int i = 0; i < 16; ++i) {
    const int n = i * 1024 + t * 4;        // boundary 12288 = iter 12 exactly
    const float4 v = *(const float4*)(row + n);
    const bool isv = n < NVAR;
    const float pv = isv ? PV : PE;
    acc += pv * (v.x * v.x + v.y * v.y + v.z * v.z + v.w * v.w);
    if (wr) {
      const float s = isv ? SV : SE;
      ushort4 o;
      o.x = f2bf(v.x * s); o.y = f2bf(v.y * s);
      o.z = f2bf(v.z * s); o.w = f2bf(v.w * s);
      *(ushort4*)(Abf + (size_t)m * NN + n) = o;
    }
  }
#pragma unroll
  for (int off = 32; off > 0; off >>= 1) acc += __shfl_down(acc, off);
  __shared__ float red[4];
  if ((t & 63) == 0) red[t >> 6] = acc;
  __syncthreads();
  if (t == 0) Dout[(size_t)b * MM + m] = red[0] + red[1] + red[2] + red[3];
}

// ------------------------------- AAt GEMM ---------------------------------
// C = X Xt with X = bf16(A[0] * sqrt(Pinv)) [4096 x 16384].
// 128x128 tile, BK=64, 4 waves each computing a 64x64 sub-tile via
// 4x4 fragments of mfma_f32_16x16x32_bf16. 1024 blocks:
//   id 0..31   : diagonal tile id, full K, store to true location.
//   id 32..1023: e=id-32; kid=(e&7)*124+(e>>3); pair=kid>>1, half=kid&1.
//                half1 -> true upper tile; half0 -> mirror slot
//                (swap tile bases, SAME local coords - no transpose).
// T2 bank-conflict fix: 16B-chunk XOR swizzle on the GLOBAL source address
// (global_load_lds writes linearly) and on the ds_read address.
template <int USE_WS>
__global__ __launch_bounds__(256, 4)
void gemm_aat(const u16* __restrict__ Abf, const float* __restrict__ A0,
              float* __restrict__ C) {
  const int id = blockIdx.x;
  int bi, bj, ktBeg, ktEnd;
  bool mirror;
  if (id < 32) {
    bi = bj = id; ktBeg = 0; ktEnd = 256; mirror = false;
  } else {
    const int e0 = id - 32;
    const int kid = (e0 & 7) * 124 + (e0 >> 3);   // XCD-chunked over 992
    const int pair = kid >> 1;
    const int half = kid & 1;
    pair_decode(pair, bi, bj);
    ktBeg = half * 128; ktEnd = ktBeg + 128;
    mirror = (half == 0);
  }

  __shared__ u16 ldsA[128 * 64];
  __shared__ u16 ldsB[128 * 64];
  const int t = threadIdx.x;
  const int lane = t & 63;
  const int wave = t >> 6;
  const int wr = (wave >> 1) * 64;   // wave's row offset in tile
  const int wc = (wave & 1) * 64;    // wave's col offset in tile

  f4v acc[4][4];
#pragma unroll
  for (int i = 0; i < 4; ++i)
#pragma unroll
    for (int j = 0; j < 4; ++j)
      acc[i][j] = f4v{0.f, 0.f, 0.f, 0.f};

  // staging: thread t fills LDS row (t>>3), 16B chunk (t&7) of each 32-row
  // block; source column chunk is XOR-swizzled so that
  // LDS[row][c] = global[row][c ^ (row&7)]  (chunks of 8 elems / 16B)
  const int srow = t >> 3;
  const int scol = (((t & 7) ^ (srow & 7)) * 8);   // swizzled source chunk
  const size_t rA = (size_t)bi * 128 + srow;
  const size_t rB = (size_t)bj * 128 + srow;
  const int ldse = t * 8;            // linear per-thread LDS elem offset

  const float SV = sqrtf(1.0f / 1e-5f);
  const float SE = sqrtf(1.0f / 1e5f);

  // ds_read swizzle: row r, chunk (kk*4+q) -> chunk ^ (r&7); r&7 == p&7
  const int q = lane >> 4;
  const int p = lane & 15;
  const int csw0 = ((0 * 4 + q) ^ (p & 7)) * 8;    // kk=0 chunk offset (elems)
  const int csw1 = ((1 * 4 + q) ^ (p & 7)) * 8;    // kk=1

  for (int kt = ktBeg; kt < ktEnd; ++kt) {
    const int kb = kt * 64;
    if (USE_WS) {
#pragma unroll
      for (int i = 0; i < 4; ++i) {
        gld_lds16(Abf + (rA + i * 32) * NN + kb + scol, &ldsA[i * 2048 + ldse]);
        gld_lds16(Abf + (rB + i * 32) * NN + kb + scol, &ldsB[i * 2048 + ldse]);
      }
    } else {
      // fallback: reg-stage fp32 -> scaled bf16 -> LDS (same swizzle)
      const int n = kb + scol;                    // 8-chunk never crosses 12288
      const float s = (n < NVAR) ? SV : SE;
#pragma unroll
      for (int i = 0; i < 4; ++i) {
        const float* ga = A0 + (rA + i * 32) * NN + n;
        const float* gb = A0 + (rB + i * 32) * NN + n;
        const float4 a0 = ((const float4*)ga)[0], a1 = ((const float4*)ga)[1];
        const float4 b0 = ((const float4*)gb)[0], b1 = ((const float4*)gb)[1];
        u16* dA = &ldsA[i * 2048 + ldse];
        u16* dB = &ldsB[i * 2048 + ldse];
        dA[0] = f2bf(a0.x * s); dA[1] = f2bf(a0.y * s);
        dA[2] = f2bf(a0.z * s); dA[3] = f2bf(a0.w * s);
        dA[4] = f2bf(a1.x * s); dA[5] = f2bf(a1.y * s);
        dA[6] = f2bf(a1.z * s); dA[7] = f2bf(a1.w * s);
        dB[0] = f2bf(b0.x * s); dB[1] = f2bf(b0.y * s);
        dB[2] = f2bf(b0.z * s); dB[3] = f2bf(b0.w * s);
        dB[4] = f2bf(b1.x * s); dB[5] = f2bf(b1.y * s);
        dB[6] = f2bf(b1.z * s); dB[7] = f2bf(b1.w * s);
      }
    }
    __syncthreads();
#pragma unroll
    for (int kk = 0; kk < 2; ++kk) {
      const int co = kk ? csw1 : csw0;
      bf8v af[4], bfr[4];
#pragma unroll
      for (int i = 0; i < 4; ++i)
        af[i] = *(const bf8v*)&ldsA[(wr + i * 16 + p) * 64 + co];
#pragma unroll
      for (int j = 0; j < 4; ++j)
        bfr[j] = *(const bf8v*)&ldsB[(wc + j * 16 + p) * 64 + co];
#pragma unroll
      for (int i = 0; i < 4; ++i)
#pragma unroll
        for (int j = 0; j < 4; ++j)
          acc[i][j] = __builtin_amdgcn_mfma_f32_16x16x32_bf16(
              af[i], bfr[j], acc[i][j], 0, 0, 0);
    }
    __syncthreads();
  }

  // epilogue: C/D layout col=lane&15 (=p), row=(lane>>4)*4+reg (=q*4+r)
  // mirror: swap tile bases, keep local coords (un-transposed partial slot)
  const int rowBase = (mirror ? bj : bi) * 128;
  const int colBase = (mirror ? bi : bj) * 128;
  const int cc = p;
  const int cr = q * 4;
#pragma unroll
  for (int i = 0; i < 4; ++i)
#pragma unroll
    for (int j = 0; j < 4; ++j)
#pragma unroll
      for (int r = 0; r < 4; ++r) {
        const int gr = rowBase + wr + i * 16 + cr + r;
        const int gc = colBase + wc + j * 16 + cc;
        C[(size_t)gr * MM + gc] = acc[i][j][r];
      }
}

// --------------------------- reduceA: upper += slot ------------------------
// 496 blocks, one per strict-upper pair. All reads/writes coalesced rows.
__global__ __launch_bounds__(256)
void reduce_sum(float* __restrict__ C) {
  int bi, bj;
  pair_decode(blockIdx.x, bi, bj);
  const int t = threadIdx.x;
#pragma unroll
  for (int k = 0; k < 16; ++k) {
    const int idx = t + k * 256;           // 4096 float4 = 128 rows x 32
    const int r = idx >> 5, c4 = idx & 31;
    float* up = C + (size_t)(bi * 128 + r) * MM + bj * 128 + c4 * 4;
    const float* lo = C + (size_t)(bj * 128 + r) * MM + bi * 128 + c4 * 4;
    float4 u = *(const float4*)up;
    float4 l = *(const float4*)lo;
    u.x += l.x; u.y += l.y; u.z += l.z; u.w += l.w;
    *(float4*)up = u;
  }
}

// --------------------- reduceB: lower = upper^T ----------------------------
// 496 blocks; LDS-staged 64-row strips; reads upper (final), writes lower.
__global__ __launch_bounds__(256)
void reduce_mirror(float* __restrict__ C) {
  int bi, bj;
  pair_decode(blockIdx.x, bi, bj);
  const int t = threadIdx.x;
  __shared__ float S[64][132];
#pragma unroll
  for (int s = 0; s < 2; ++s) {
#pragma unroll
    for (int k = 0; k < 8; ++k) {          // 2048 float4 = 64 rows x 32
      const int idx = t + k * 256;
      const int r = idx >> 5, c4 = idx & 31;
      const float4 v = *(const float4*)(C + (size_t)(bi * 128 + s * 64 + r) * MM +
                                        bj * 128 + c4 * 4);
      S[r][c4 * 4 + 0] = v.x; S[r][c4 * 4 + 1] = v.y;
      S[r][c4 * 4 + 2] = v.z; S[r][c4 * 4 + 3] = v.w;
    }
    __syncthreads();
#pragma unroll
    for (int k = 0; k < 8; ++k) {          // 2048 float4 = 128 rows x 16
      const int idx = t + k * 256;
      const int c = idx >> 4, r4 = idx & 15;
      float4 w;
      w.x = S[r4 * 4 + 0][c]; w.y = S[r4 * 4 + 1][c];
      w.z = S[r4 * 4 + 2][c]; w.w = S[r4 * 4 + 3][c];
      *(float4*)(C + (size_t)(bj * 128 + c) * MM + bi * 128 + s * 64 + r4 * 4) = w;
    }
    __syncthreads();
  }
}

// ------------------------------- launch ------------------------------------
extern "C" void kernel_launch(void* const* d_in, const int* in_sizes, int n_in,
                              void* d_out, int out_size, void* d_ws,
                              size_t ws_size, hipStream_t stream) {
  const float* coeffs = (const float*)d_in[0];
  const float* rhs    = (const float*)d_in[1];
  const float* stx    = (const float*)d_in[2];
  const float* sty    = (const float*)d_in[3];
  const float* A      = (const float*)d_in[4];

  float* out    = (float*)d_out;
  float* outAAt = out + 14460;
  float* outD   = out + 16791676;

  const size_t need = (size_t)MM * NN * sizeof(u16);  // 128 MiB
  const int useWs = (ws_size >= need) ? 1 : 0;
  u16* Abf = (u16*)d_ws;

  small_ops<<<dim3(57), dim3(256), 0, stream>>>(coeffs, rhs, stx, sty, out);
  d_and_convert<<<dim3(MM, 2), dim3(256), 0, stream>>>(A, outD, Abf, useWs);
  if (useWs)
    gemm_aat<1><<<dim3(1024), dim3(256), 0, stream>>>(Abf, A, outAAt);
  else
    gemm_aat<0><<<dim3(1024), dim3(256), 0, stream>>>(Abf, A, outAAt);
  reduce_sum<<<dim3(496), dim3(256), 0, stream>>>(outAAt);
  reduce_mirror<<<dim3(496), dim3(256), 0, stream>>>(outAAt);
}

// Round 8
// 541.667 us; speedup vs baseline: 1.7828x; 1.0261x over previous
//
#include <hip/hip_runtime.h>
#include <cstddef>

// ---------------------------------------------------------------------------
// MultigridLayer: c/r bilinear downsample + steps pair-sum + AAt (bf16 MFMA,
// symmetric, Pinv folded as sqrt into columns) + D row-weighted-sumsq.
//
// Output layout (fp32, flat):
//   c   [2][1024][6]     @ 0         (12288)
//   r   [2][1024]        @ 12288     (2048)
//   sx  [2][31]          @ 14336     (62)
//   sy  [2][31]          @ 14398     (62)
//   AAt [1][4096][4096]  @ 14460     (16777216)
//   D   [2][4096]        @ 16791676  (8192)
//
// GEMM work decomposition (no atomics, 4 blocks/CU):
//   1024 blocks = 32 diagonal tiles (full K) + 496 strict-upper pairs x 2
//   K-halves. half1 -> partial to true upper tile; half0 -> partial
//   (un-transposed) to the mirror (lower) slot. reduceA: upper += lowerSlot.
//   reduceB: lowerSlot = upper^T (LDS-staged transpose). m97 2-barrier body,
//   T2 XOR swizzle (bank conflicts = 0 measured).
// R8 (= R7 retry): non-temporal stores for C partials + NT loads for
//   single-use streams, keeping the 128 MB Abf panel set resident in the
//   Infinity Cache (R6: FETCH 1.13 GB for a 128 MB L3-fittable input =
//   thrash). NT builtins require ext_vector_type pointers (not HIP float4).
// ---------------------------------------------------------------------------

#define NVAR 12288
#define NN   16384   // NUM_VAR + NUM_EPS (K dim of the GEMM)
#define MM   4096    // NUM_EPS (M=N of AAt)

typedef __bf16 bf8v __attribute__((ext_vector_type(8)));
typedef float  f4v  __attribute__((ext_vector_type(4)));
typedef unsigned short u16;

__device__ __forceinline__ void gld_lds16(const void* g, void* l) {
  __builtin_amdgcn_global_load_lds((const __attribute__((address_space(1))) void*)g,
                                   (__attribute__((address_space(3))) void*)l,
                                   16, 0, 0);
}

// round-to-nearest-even fp32 -> bf16 (finite values only)
__device__ __forceinline__ u16 f2bf(float x) {
  unsigned int u = __float_as_uint(x);
  u = (u + 0x7fffu + ((u >> 16) & 1u)) >> 16;
  return (u16)u;
}

// jax.image.resize linear+antialias, scale=1/2: taps at 2i-1..2i+2, raw
// weights {.25,.75,.75,.25}, out-of-range dropped, renormalized.
__device__ __forceinline__ void make_taps(int i, float w[4], int p[4]) {
  const float rw[4] = {0.25f, 0.75f, 0.75f, 0.25f};
  float s = 0.f;
#pragma unroll
  for (int t = 0; t < 4; ++t) {
    int pp = 2 * i - 1 + t;
    bool v = (pp >= 0) && (pp < 64);
    p[t] = v ? pp : 0;
    w[t] = v ? rw[t] : 0.f;
    s += w[t];
  }
  float inv = 1.f / s;
#pragma unroll
  for (int t = 0; t < 4; ++t) w[t] *= inv;
}

// strict-upper pair decode over a 32x32 tile grid: pair p -> (bi, bj), bi<bj
// C(i) = i*(63-i)/2 pairs before row i.
__device__ __forceinline__ void pair_decode(int pair, int& bi, int& bj) {
  int i = 0;
  while (((i + 1) * (63 - (i + 1))) / 2 <= pair) ++i;
  bi = i;
  bj = i + 1 + (pair - (i * (63 - i)) / 2);
}

// --------------------------- small outputs --------------------------------
__global__ void small_ops(const float* __restrict__ coeffs,
                          const float* __restrict__ rhs,
                          const float* __restrict__ stx,
                          const float* __restrict__ sty,
                          float* __restrict__ out) {
  int idx = blockIdx.x * 256 + threadIdx.x;
  if (idx < 12288) {                       // c: [b][pix][o]
    int b = idx / 6144, rem = idx % 6144;
    int pix = rem / 6, o = rem % 6;
    int yi = pix >> 5, xi = pix & 31;
    float wy[4], wx[4]; int py[4], px[4];
    make_taps(yi, wy, py);
    make_taps(xi, wx, px);
    float acc = 0.f;
#pragma unroll
    for (int dy = 0; dy < 4; ++dy) {
      float sx = 0.f;
#pragma unroll
      for (int dx = 0; dx < 4; ++dx)
        sx += wx[dx] * coeffs[((size_t)b * 4096 + py[dy] * 64 + px[dx]) * 6 + o];
      acc += wy[dy] * sx;
    }
    out[idx] = acc;
  } else if (idx < 14336) {                // r: [b][pix]
    int j = idx - 12288;
    int b = j >> 10, pix = j & 1023;
    int yi = pix >> 5, xi = pix & 31;
    float wy[4], wx[4]; int py[4], px[4];
    make_taps(yi, wy, py);
    make_taps(xi, wx, px);
    float acc = 0.f;
#pragma unroll
    for (int dy = 0; dy < 4; ++dy) {
      float sx = 0.f;
#pragma unroll
      for (int dx = 0; dx < 4; ++dx)
        sx += wx[dx] * rhs[(size_t)b * 4096 + py[dy] * 64 + px[dx]];
      acc += wy[dy] * sx;
    }
    out[idx] = acc;
  } else if (idx < 14460) {                // sx then sy: pair sums
    int j = idx - 14336;
    if (j < 62) {
      int b = j / 31, i = j % 31;
      out[idx] = stx[b * 63 + 2 * i] + stx[b * 63 + 2 * i + 1];
    } else {
      j -= 62;
      int b = j / 31, i = j % 31;
      out[idx] = sty[b * 63 + 2 * i] + sty[b * 63 + 2 * i + 1];
    }
  }
}

// ------------------- D + fused bf16*sqrt(Pinv) convert ---------------------
// one block per (row m, batch b); 256 threads read the 16384-float row.
// A is streamed once -> non-temporal loads (keep L3 for Abf).
__global__ __launch_bounds__(256)
void d_and_convert(const float* __restrict__ A, float* __restrict__ Dout,
                   u16* __restrict__ Abf, const int useWs) {
  const int m = blockIdx.x, b = blockIdx.y;
  const int t = threadIdx.x;
  const float PV = 1.0f / 1e-5f, PE = 1.0f / 1e5f;
  const float SV = sqrtf(PV), SE = sqrtf(PE);
  const float* __restrict__ row = A + ((size_t)b * MM + m) * NN;
  const bool wr = (b == 0) && useWs;
  float acc = 0.f;
#pragma unroll
  for (int i = 0; i < 16; ++i) {
    const int n = i * 1024 + t * 4;        // boundary 12288 = iter 12 exactly
    const f4v v = __builtin_nontemporal_load((const f4v*)(row + n));
    const bool isv = n < NVAR;
    const float pv = isv ? PV : PE;
    acc += pv * (v.x * v.x + v.y * v.y + v.z * v.z + v.w * v.w);
    if (wr) {
      const float s = isv ? SV : SE;
      ushort4 o;
      o.x = f2bf(v.x * s); o.y = f2bf(v.y * s);
      o.z = f2bf(v.z * s); o.w = f2bf(v.w * s);
      *(ushort4*)(Abf + (size_t)m * NN + n) = o;   // re-read by gemm: temporal
    }
  }
#pragma unroll
  for (int off = 32; off > 0; off >>= 1) acc += __shfl_down(acc, off);
  __shared__ float red[4];
  if ((t & 63) == 0) red[t >> 6] = acc;
  __syncthreads();
  if (t == 0) Dout[(size_t)b * MM + m] = red[0] + red[1] + red[2] + red[3];
}

// ------------------------------- AAt GEMM ---------------------------------
// C = X Xt with X = bf16(A[0] * sqrt(Pinv)) [4096 x 16384].
// 128x128 tile, BK=64, 4 waves each computing a 64x64 sub-tile via
// 4x4 fragments of mfma_f32_16x16x32_bf16. 1024 blocks:
//   id 0..31   : diagonal tile id, full K, store to true location.
//   id 32..1023: e=id-32; kid=(e&7)*124+(e>>3); pair=kid>>1, half=kid&1.
//                half1 -> true upper tile; half0 -> mirror slot
//                (swap tile bases, SAME local coords - no transpose).
// T2 bank-conflict fix: 16B-chunk XOR swizzle on the GLOBAL source address
// (global_load_lds writes linearly) and on the ds_read address.
// C partials: non-temporal stores (read once by reduce; keep L3 for Abf).
template <int USE_WS>
__global__ __launch_bounds__(256, 4)
void gemm_aat(const u16* __restrict__ Abf, const float* __restrict__ A0,
              float* __restrict__ C) {
  const int id = blockIdx.x;
  int bi, bj, ktBeg, ktEnd;
  bool mirror;
  if (id < 32) {
    bi = bj = id; ktBeg = 0; ktEnd = 256; mirror = false;
  } else {
    const int e0 = id - 32;
    const int kid = (e0 & 7) * 124 + (e0 >> 3);   // XCD-chunked over 992
    const int pair = kid >> 1;
    const int half = kid & 1;
    pair_decode(pair, bi, bj);
    ktBeg = half * 128; ktEnd = ktBeg + 128;
    mirror = (half == 0);
  }

  __shared__ u16 ldsA[128 * 64];
  __shared__ u16 ldsB[128 * 64];
  const int t = threadIdx.x;
  const int lane = t & 63;
  const int wave = t >> 6;
  const int wr = (wave >> 1) * 64;   // wave's row offset in tile
  const int wc = (wave & 1) * 64;    // wave's col offset in tile

  f4v acc[4][4];
#pragma unroll
  for (int i = 0; i < 4; ++i)
#pragma unroll
    for (int j = 0; j < 4; ++j)
      acc[i][j] = f4v{0.f, 0.f, 0.f, 0.f};

  // staging: thread t fills LDS row (t>>3), 16B chunk (t&7) of each 32-row
  // block; source column chunk is XOR-swizzled so that
  // LDS[row][c] = global[row][c ^ (row&7)]  (chunks of 8 elems / 16B)
  const int srow = t >> 3;
  const int scol = (((t & 7) ^ (srow & 7)) * 8);   // swizzled source chunk
  const size_t rA = (size_t)bi * 128 + srow;
  const size_t rB = (size_t)bj * 128 + srow;
  const int ldse = t * 8;            // linear per-thread LDS elem offset

  const float SV = sqrtf(1.0f / 1e-5f);
  const float SE = sqrtf(1.0f / 1e5f);

  // ds_read swizzle: row r, chunk (kk*4+q) -> chunk ^ (r&7); r&7 == p&7
  const int q = lane >> 4;
  const int p = lane & 15;
  const int csw0 = ((0 * 4 + q) ^ (p & 7)) * 8;    // kk=0 chunk offset (elems)
  const int csw1 = ((1 * 4 + q) ^ (p & 7)) * 8;    // kk=1

  for (int kt = ktBeg; kt < ktEnd; ++kt) {
    const int kb = kt * 64;
    if (USE_WS) {
#pragma unroll
      for (int i = 0; i < 4; ++i) {
        gld_lds16(Abf + (rA + i * 32) * NN + kb + scol, &ldsA[i * 2048 + ldse]);
        gld_lds16(Abf + (rB + i * 32) * NN + kb + scol, &ldsB[i * 2048 + ldse]);
      }
    } else {
      // fallback: reg-stage fp32 -> scaled bf16 -> LDS (same swizzle)
      const int n = kb + scol;                    // 8-chunk never crosses 12288
      const float s = (n < NVAR) ? SV : SE;
#pragma unroll
      for (int i = 0; i < 4; ++i) {
        const float* ga = A0 + (rA + i * 32) * NN + n;
        const float* gb = A0 + (rB + i * 32) * NN + n;
        const f4v a0 = ((const f4v*)ga)[0], a1 = ((const f4v*)ga)[1];
        const f4v b0 = ((const f4v*)gb)[0], b1 = ((const f4v*)gb)[1];
        u16* dA = &ldsA[i * 2048 + ldse];
        u16* dB = &ldsB[i * 2048 + ldse];
        dA[0] = f2bf(a0.x * s); dA[1] = f2bf(a0.y * s);
        dA[2] = f2bf(a0.z * s); dA[3] = f2bf(a0.w * s);
        dA[4] = f2bf(a1.x * s); dA[5] = f2bf(a1.y * s);
        dA[6] = f2bf(a1.z * s); dA[7] = f2bf(a1.w * s);
        dB[0] = f2bf(b0.x * s); dB[1] = f2bf(b0.y * s);
        dB[2] = f2bf(b0.z * s); dB[3] = f2bf(b0.w * s);
        dB[4] = f2bf(b1.x * s); dB[5] = f2bf(b1.y * s);
        dB[6] = f2bf(b1.z * s); dB[7] = f2bf(b1.w * s);
      }
    }
    __syncthreads();
#pragma unroll
    for (int kk = 0; kk < 2; ++kk) {
      const int co = kk ? csw1 : csw0;
      bf8v af[4], bfr[4];
#pragma unroll
      for (int i = 0; i < 4; ++i)
        af[i] = *(const bf8v*)&ldsA[(wr + i * 16 + p) * 64 + co];
#pragma unroll
      for (int j = 0; j < 4; ++j)
        bfr[j] = *(const bf8v*)&ldsB[(wc + j * 16 + p) * 64 + co];
#pragma unroll
      for (int i = 0; i < 4; ++i)
#pragma unroll
        for (int j = 0; j < 4; ++j)
          acc[i][j] = __builtin_amdgcn_mfma_f32_16x16x32_bf16(
              af[i], bfr[j], acc[i][j], 0, 0, 0);
    }
    __syncthreads();
  }

  // epilogue: C/D layout col=lane&15 (=p), row=(lane>>4)*4+reg (=q*4+r)
  // mirror: swap tile bases, keep local coords (un-transposed partial slot)
  // NT stores: partials are read exactly once (reduce) or never re-read.
  const int rowBase = (mirror ? bj : bi) * 128;
  const int colBase = (mirror ? bi : bj) * 128;
  const int cc = p;
  const int cr = q * 4;
#pragma unroll
  for (int i = 0; i < 4; ++i)
#pragma unroll
    for (int j = 0; j < 4; ++j)
#pragma unroll
      for (int r = 0; r < 4; ++r) {
        const int gr = rowBase + wr + i * 16 + cr + r;
        const int gc = colBase + wc + j * 16 + cc;
        __builtin_nontemporal_store(acc[i][j][r], &C[(size_t)gr * MM + gc]);
      }
}

// --------------------------- reduceA: upper += slot ------------------------
// 496 blocks, one per strict-upper pair. All reads/writes coalesced rows.
// lower-slot partial: last use -> NT load. upper: re-read by mirror -> keep.
__global__ __launch_bounds__(256)
void reduce_sum(float* __restrict__ C) {
  int bi, bj;
  pair_decode(blockIdx.x, bi, bj);
  const int t = threadIdx.x;
#pragma unroll
  for (int k = 0; k < 16; ++k) {
    const int idx = t + k * 256;           // 4096 float4 = 128 rows x 32
    const int r = idx >> 5, c4 = idx & 31;
    float* up = C + (size_t)(bi * 128 + r) * MM + bj * 128 + c4 * 4;
    const float* lo = C + (size_t)(bj * 128 + r) * MM + bi * 128 + c4 * 4;
    f4v u = *(const f4v*)up;
    const f4v l = __builtin_nontemporal_load((const f4v*)lo);
    u += l;
    *(f4v*)up = u;
  }
}

// --------------------- reduceB: lower = upper^T ----------------------------
// 496 blocks; LDS-staged 64-row strips; reads upper (final), writes lower.
// Both sides last-use -> NT.
__global__ __launch_bounds__(256)
void reduce_mirror(float* __restrict__ C) {
  int bi, bj;
  pair_decode(blockIdx.x, bi, bj);
  const int t = threadIdx.x;
  __shared__ float S[64][132];
#pragma unroll
  for (int s = 0; s < 2; ++s) {
#pragma unroll
    for (int k = 0; k < 8; ++k) {          // 2048 float4 = 64 rows x 32
      const int idx = t + k * 256;
      const int r = idx >> 5, c4 = idx & 31;
      const f4v v = __builtin_nontemporal_load(
          (const f4v*)(C + (size_t)(bi * 128 + s * 64 + r) * MM +
                       bj * 128 + c4 * 4));
      S[r][c4 * 4 + 0] = v.x; S[r][c4 * 4 + 1] = v.y;
      S[r][c4 * 4 + 2] = v.z; S[r][c4 * 4 + 3] = v.w;
    }
    __syncthreads();
#pragma unroll
    for (int k = 0; k < 8; ++k) {          // 2048 float4 = 128 rows x 16
      const int idx = t + k * 256;
      const int c = idx >> 4, r4 = idx & 15;
      f4v w;
      w.x = S[r4 * 4 + 0][c]; w.y = S[r4 * 4 + 1][c];
      w.z = S[r4 * 4 + 2][c]; w.w = S[r4 * 4 + 3][c];
      __builtin_nontemporal_store(
          w, (f4v*)(C + (size_t)(bj * 128 + c) * MM + bi * 128 +
                    s * 64 + r4 * 4));
    }
    __syncthreads();
  }
}

// ------------------------------- launch ------------------------------------
extern "C" void kernel_launch(void* const* d_in, const int* in_sizes, int n_in,
                              void* d_out, int out_size, void* d_ws,
                              size_t ws_size, hipStream_t stream) {
  const float* coeffs = (const float*)d_in[0];
  const float* rhs    = (const float*)d_in[1];
  const float* stx    = (const float*)d_in[2];
  const float* sty    = (const float*)d_in[3];
  const float* A      = (const float*)d_in[4];

  float* out    = (float*)d_out;
  float* outAAt = out + 14460;
  float* outD   = out + 16791676;

  const size_t need = (size_t)MM * NN * sizeof(u16);  // 128 MiB
  const int useWs = (ws_size >= need) ? 1 : 0;
  u16* Abf = (u16*)d_ws;

  small_ops<<<dim3(57), dim3(256), 0, stream>>>(coeffs, rhs, stx, sty, out);
  d_and_convert<<<dim3(MM, 2), dim3(256), 0, stream>>>(A, outD, Abf, useWs);
  if (useWs)
    gemm_aat<1><<<dim3(1024), dim3(256), 0, stream>>>(Abf, A, outAAt);
  else
    gemm_aat<0><<<dim3(1024), dim3(256), 0, stream>>>(Abf, A, outAAt);
  reduce_sum<<<dim3(496), dim3(256), 0, stream>>>(outAAt);
  reduce_mirror<<<dim3(496), dim3(256), 0, stream>>>(outAAt);
}